// Round 7
// baseline (250.457 us; speedup 1.0000x reference)
//
#include <hip/hip_runtime.h>
#include <hip/hip_bf16.h>

// ---------------------------------------------------------------------------
// MHSelfAttention: out = softmax((X Wq)(X Wk)^T / sqrt(1024)) (X Wv), 16 heads
// Round 7: attn restored to the r3-proven kernel (defer-max, single-buffer,
// 2 barriers). GEMM upgraded to the catalog-verified 2-phase template:
// dbuf BK=32, STAGE(next) issued before compute(cur), one __syncthreads per
// K-step (built-in vmcnt/lgkmcnt drain = safe by construction). + XCD swizzle.
// ---------------------------------------------------------------------------

typedef __attribute__((ext_vector_type(8))) __bf16 bf16x8;
typedef __attribute__((ext_vector_type(8))) unsigned short u16x8;
typedef __attribute__((ext_vector_type(4))) unsigned short u16x4;
typedef __attribute__((ext_vector_type(4))) float f32x4;

#define B_  4
#define S_  2048
#define H_  1024
#define NH_ 16
#define HD_ 64
#define N3_ 3072
#define M_  (B_*S_)   // 8192

static __device__ __forceinline__ unsigned short f2bf(float f) {
  __bf16 h = (__bf16)f;
  return __builtin_bit_cast(unsigned short, h);
}

static __device__ __forceinline__ float exp2_fast(float x) {
  float r; asm("v_exp_f32 %0, %1" : "=v"(r) : "v"(x)); return r;
}

// async global->LDS, 16B per lane; LDS dst = wave-uniform base + lane*16
static __device__ __forceinline__ void gload_lds16(const unsigned short* g,
                                                   unsigned short* l) {
  __builtin_amdgcn_global_load_lds(
      (const __attribute__((address_space(1))) unsigned int*)g,
      (__attribute__((address_space(3))) unsigned int*)l, 16, 0, 0);
}

// ---- kernel 1: embeddings fp32 -> bf16 ------------------------------------
__global__ __launch_bounds__(256) void cvt_emb_kernel(
    const float* __restrict__ in, unsigned short* __restrict__ out, int n4) {
  int i = blockIdx.x * blockDim.x + threadIdx.x;
  int stride = gridDim.x * blockDim.x;
  const float4* in4 = (const float4*)in;
  for (; i < n4; i += stride) {
    float4 v = in4[i];
    ushort4 o;
    o.x = f2bf(v.x); o.y = f2bf(v.y); o.z = f2bf(v.z); o.w = f2bf(v.w);
    ((ushort4*)out)[i] = o;
  }
}

// ---- kernel 2: w fp32 [1024][3072] -> bf16 [3072][1024], LDS-tiled --------
__global__ __launch_bounds__(256) void cvt_w_kernel(
    const float* __restrict__ in, unsigned short* __restrict__ out) {
  __shared__ __align__(16) unsigned short tile[64 * 64];
  const int t = threadIdx.x;
  const int n0 = blockIdx.x * 64;
  const int k0 = blockIdx.y * 64;
#pragma unroll
  for (int it = 0; it < 4; ++it) {
    int c = it * 256 + t;
    int row = c >> 4;
    int a = c & 15;
    float4 v = *(const float4*)(in + (size_t)(k0 + row) * N3_ + n0 + a * 4);
    u16x4 o;
    o[0] = f2bf(v.x); o[1] = f2bf(v.y); o[2] = f2bf(v.z); o[3] = f2bf(v.w);
    int swz = (((row & 7) ^ ((row >> 3) & 7)) << 4);
    *(u16x4*)((char*)tile + row * 128 + ((a * 8) ^ swz)) = o;
  }
  __syncthreads();
#pragma unroll
  for (int it = 0; it < 2; ++it) {
    int c = it * 256 + t;
    int n = c >> 3;
    int a = c & 7;
    u16x8 o;
#pragma unroll
    for (int j = 0; j < 8; ++j) {
      int k = a * 8 + j;
      int swz = (((k & 7) ^ ((k >> 3) & 7)) << 4);
      o[j] = *(const unsigned short*)((char*)tile + k * 128 + ((2 * n) ^ swz));
    }
    *(u16x8*)(out + (size_t)(n0 + n) * H_ + k0 + a * 8) = o;
  }
}

// ---- kernel 3: QKV GEMM, 2-phase dbuf (T3 minimum recipe) -----------------
// 128x128 tile, BK=32, 4 waves (2x2). Double-buffered LDS; STAGE(tile t+1)
// issued BEFORE compute(tile t); one __syncthreads per K-step (its built-in
// vmcnt(0)+lgkmcnt(0) drain makes the dbuf safe with no inline-asm fences).
// LDS rows 64B; chunk involution ^(row&3) on source + read (G21).
__global__ __launch_bounds__(256, 3) void qkv_gemm_kernel(
    const unsigned short* __restrict__ A,
    const unsigned short* __restrict__ BT,
    unsigned short* __restrict__ C) {
  __shared__ __align__(16) unsigned short lds[2][2][128 * 32];  // 32KB
  const int t = threadIdx.x;
  const int lane = t & 63;
  const int w = t >> 6;
  const int wm = w >> 1, wn = w & 1;
  // bijective XCD-chunked swizzle over 1536 blocks (24 n-blocks x 64 m-blocks)
  const int wg = blockIdx.x;
  const int swz = (wg & 7) * 192 + (wg >> 3);
  const int n0 = (swz % 24) * 128;
  const int m0 = (swz / 24) * 128;
  const int lr = lane & 15;
  const int lh = lane >> 4;
  const int ach = (lh ^ (lr & 3)) * 16;   // frag read chunk (bytes), row&3==lr&3

  // staging: lane covers row w*16 + (lane>>2) (and +64), 16B chunk lane&3;
  // source chunk pre-swizzled by the same involution ^(row&3)
  const int srow = w * 16 + (lane >> 2);
  const int sch = (lane & 3) ^ ((lane >> 2) & 3);
  const unsigned short* As = A + (size_t)(m0 + srow) * H_ + sch * 8;
  const unsigned short* Bs = BT + (size_t)(n0 + srow) * H_ + sch * 8;

#define STAGE(SB, KT)                                                        \
  do {                                                                       \
    gload_lds16(As + (size_t)(KT) * 32, &lds[SB][0][(w * 16) * 32]);         \
    gload_lds16(As + 64 * (size_t)H_ + (size_t)(KT) * 32,                    \
                &lds[SB][0][(64 + w * 16) * 32]);                            \
    gload_lds16(Bs + (size_t)(KT) * 32, &lds[SB][1][(w * 16) * 32]);         \
    gload_lds16(Bs + 64 * (size_t)H_ + (size_t)(KT) * 32,                    \
                &lds[SB][1][(64 + w * 16) * 32]);                            \
  } while (0)

  f32x4 acc[4][4];
#pragma unroll
  for (int i = 0; i < 4; i++)
#pragma unroll
    for (int j = 0; j < 4; j++)
#pragma unroll
      for (int r = 0; r < 4; r++) acc[i][j][r] = 0.f;

  STAGE(0, 0);
  __syncthreads();                      // tile 0 landed (auto vmcnt drain)

  for (int kt = 0; kt < 32; ++kt) {
    const int cur = kt & 1;
    if (kt < 31) STAGE(cur ^ 1, kt + 1);  // overlap DMA with compute below
    bf16x8 af[4], bfr[4];
#pragma unroll
    for (int mi = 0; mi < 4; ++mi)
      af[mi] = *(const bf16x8*)((const char*)&lds[cur][0][0] +
                                (wm * 64 + mi * 16 + lr) * 64 + ach);
#pragma unroll
    for (int ni = 0; ni < 4; ++ni)
      bfr[ni] = *(const bf16x8*)((const char*)&lds[cur][1][0] +
                                 (wn * 64 + ni * 16 + lr) * 64 + ach);
#pragma unroll
    for (int mi = 0; mi < 4; ++mi)
#pragma unroll
      for (int ni = 0; ni < 4; ++ni)
        acc[mi][ni] = __builtin_amdgcn_mfma_f32_16x16x32_bf16(
            af[mi], bfr[ni], acc[mi][ni], 0, 0, 0);
    __syncthreads();  // drains next-tile DMA + this tile's reads; flip safe
  }
#undef STAGE

  const float mult = (n0 < H_) ? 0.045084220027780106f : 1.0f;  // log2e/32
#pragma unroll
  for (int mi = 0; mi < 4; mi++)
#pragma unroll
    for (int ni = 0; ni < 4; ni++)
#pragma unroll
      for (int rg = 0; rg < 4; rg++) {
        int row = m0 + wm * 64 + mi * 16 + lh * 4 + rg;
        int col = n0 + wn * 64 + ni * 16 + lr;
        C[(size_t)row * N3_ + col] = f2bf(acc[mi][ni][rg] * mult);
      }
}

// ---- kernel 4: V transpose -> vt [b][h][d][s], pi-permuted 8B slots -------
__global__ __launch_bounds__(256) void vtrans_kernel(
    const unsigned short* __restrict__ qkv, unsigned short* __restrict__ vt) {
  __shared__ __align__(16) unsigned short tile[64 * 64];
  const int t = threadIdx.x;
  const int st = blockIdx.x;
  const int h = blockIdx.y;
  const int b = blockIdx.z;
  const int s0 = st * 64;
#pragma unroll
  for (int it = 0; it < 2; ++it) {
    int c = it * 256 + t;
    int row = c >> 3;            // s-local
    int a = c & 7;               // d-chunk
    u16x8 v = *(const u16x8*)(qkv + (size_t)(b * S_ + s0 + row) * N3_ +
                              2 * H_ + h * HD_ + a * 8);
    int swz = (((row & 7) ^ ((row >> 3) & 7)) << 4);
    *(u16x8*)((char*)tile + row * 128 + ((a * 16) ^ swz)) = v;
  }
  __syncthreads();
#pragma unroll
  for (int it = 0; it < 2; ++it) {
    int c = it * 256 + t;
    int d = c >> 3;
    int a = c & 7;               // s-chunk (8 values)
    u16x8 o;
#pragma unroll
    for (int j = 0; j < 8; ++j) {
      int r = a * 8 + j;
      int swz = (((r & 7) ^ ((r >> 3) & 7)) << 4);
      o[j] = *(const unsigned short*)((char*)tile + r * 128 + ((2 * d) ^ swz));
    }
    int s0a = a * 8, s0b = a * 8 + 4;
    int p_lo = ((s0a >> 5) << 3) | (((s0a >> 2) & 3) << 1) | ((s0a >> 4) & 1);
    int p_hi = ((s0b >> 5) << 3) | (((s0b >> 2) & 3) << 1) | ((s0b >> 4) & 1);
    unsigned short* dst =
        vt + ((size_t)((b * NH_ + h) * HD_) + d) * S_ + s0;
    u16x4 lo = {o[0], o[1], o[2], o[3]};
    u16x4 hi = {o[4], o[5], o[6], o[7]};
    *(u16x4*)(dst + p_lo * 4) = lo;
    *(u16x4*)(dst + p_hi * 4) = hi;
  }
}

// ---- kernel 5: flash attention — r3-PROVEN kernel, verbatim ---------------
// grid (16, 16, 4), 256 thr. Wave owns 32 q-rows. Defer-max softmax (thr 8),
// lsum via ones-column MFMA, single-buffer LDS with 2 barriers per tile.
__global__ __launch_bounds__(256, 3) void attn_kernel(
    const unsigned short* __restrict__ QKV,
    const unsigned short* __restrict__ VT,
    float* __restrict__ out) {
  __shared__ __align__(16) unsigned short k_lds[64 * 64];
  __shared__ __align__(16) unsigned short vt_lds[64 * 64];
  const int t = threadIdx.x;
  const int lane = t & 63;
  const int w = t >> 6;
  const int lr = lane & 15, lh = lane >> 4;
  const int h = blockIdx.y;
  const int b = blockIdx.z;
  const int qw = blockIdx.x * 128 + w * 32;

  // Q fragments (already scaled by log2e/32)
  bf16x8 qf[2][2];
#pragma unroll
  for (int qi = 0; qi < 2; ++qi) {
    const unsigned short* qp =
        QKV + (size_t)(b * S_ + qw + qi * 16 + lr) * N3_ + h * HD_ + lh * 8;
    qf[qi][0] = *(const bf16x8*)qp;
    qf[qi][1] = *(const bf16x8*)(qp + 32);
  }

  // ones B-frag: V-row d=0 equal to 1 -> PV also accumulates row-sum at d=0
  bf16x8 ones;
#pragma unroll
  for (int j = 0; j < 8; ++j) ones[j] = (lr == 0) ? (__bf16)1.0f : (__bf16)0.0f;

  f32x4 o[2][4], o5[2];
#pragma unroll
  for (int qi = 0; qi < 2; ++qi) {
#pragma unroll
    for (int i = 0; i < 4; i++)
#pragma unroll
      for (int r = 0; r < 4; r++) o[qi][i][r] = 0.f;
#pragma unroll
    for (int r = 0; r < 4; r++) o5[qi][r] = 0.f;
  }
  float mrun[2] = {-3e38f, -3e38f};

  // staging: thread covers chunks t and t+256 of each 64x64 tile
  const int row0 = t >> 3, a0 = t & 7;
  const int row1 = (256 + t) >> 3, a1 = t & 7;
  const int dst0 = row0 * 128 + ((a0 * 16) ^ ((row0 & 7) << 4));
  const int dst1 = row1 * 128 + ((a1 * 16) ^ ((row1 & 7) << 4));
  const unsigned short* kbase = QKV + (size_t)(b * S_) * N3_ + H_ + h * HD_;
  const unsigned short* vbase = VT + (size_t)((b * NH_ + h) * HD_) * S_;

  u16x8 gk0 = *(const u16x8*)(kbase + (size_t)row0 * N3_ + a0 * 8);
  u16x8 gk1 = *(const u16x8*)(kbase + (size_t)row1 * N3_ + a1 * 8);
  u16x8 gv0 = *(const u16x8*)(vbase + (size_t)row0 * S_ + a0 * 8);
  u16x8 gv1 = *(const u16x8*)(vbase + (size_t)row1 * S_ + a1 * 8);

  for (int kt = 0; kt < 32; ++kt) {
    __syncthreads();                       // prior LDS reads done
    *(u16x8*)((char*)k_lds + dst0) = gk0;
    *(u16x8*)((char*)k_lds + dst1) = gk1;
    *(u16x8*)((char*)vt_lds + dst0) = gv0;
    *(u16x8*)((char*)vt_lds + dst1) = gv1;
    __syncthreads();                       // tile ready

    // issue next-tile loads now; latency hides under compute (T14)
    {
      int ktn = (kt + 1) & 31;
      const unsigned short* kp = kbase + (size_t)(ktn * 64) * N3_;
      const unsigned short* vp = vbase + ktn * 64;
      gk0 = *(const u16x8*)(kp + (size_t)row0 * N3_ + a0 * 8);
      gk1 = *(const u16x8*)(kp + (size_t)row1 * N3_ + a1 * 8);
      gv0 = *(const u16x8*)(vp + (size_t)row0 * S_ + a0 * 8);
      gv1 = *(const u16x8*)(vp + (size_t)row1 * S_ + a1 * 8);
    }

    // ---- S^T = K Q^T (base-2-scaled) ----
    f32x4 sacc[2][4];
#pragma unroll
    for (int qi = 0; qi < 2; ++qi)
#pragma unroll
      for (int nt = 0; nt < 4; nt++)
#pragma unroll
        for (int r = 0; r < 4; r++) sacc[qi][nt][r] = 0.f;
#pragma unroll
    for (int nt = 0; nt < 4; ++nt) {
#pragma unroll
      for (int kb = 0; kb < 2; ++kb) {
        int row = nt * 16 + lr;
        bf16x8 kf = *(const bf16x8*)((char*)k_lds + row * 128 +
                                     ((64 * kb + 16 * lh) ^ ((row & 7) << 4)));
        sacc[0][nt] = __builtin_amdgcn_mfma_f32_16x16x32_bf16(kf, qf[0][kb], sacc[0][nt], 0, 0, 0);
        sacc[1][nt] = __builtin_amdgcn_mfma_f32_16x16x32_bf16(kf, qf[1][kb], sacc[1][nt], 0, 0, 0);
      }
    }

    // ---- tile max per q-subtile (row q=lr, spread over lh groups) ----
    float mx[2];
#pragma unroll
    for (int qi = 0; qi < 2; ++qi) {
      float m = fmaxf(fmaxf(fmaxf(sacc[qi][0][0], sacc[qi][0][1]),
                            fmaxf(sacc[qi][0][2], sacc[qi][0][3])),
                      fmaxf(fmaxf(sacc[qi][1][0], sacc[qi][1][1]),
                            fmaxf(sacc[qi][1][2], sacc[qi][1][3])));
      float m2 = fmaxf(fmaxf(fmaxf(sacc[qi][2][0], sacc[qi][2][1]),
                             fmaxf(sacc[qi][2][2], sacc[qi][2][3])),
                       fmaxf(fmaxf(sacc[qi][3][0], sacc[qi][3][1]),
                             fmaxf(sacc[qi][3][2], sacc[qi][3][3])));
      m = fmaxf(m, m2);
      m = fmaxf(m, __shfl_xor(m, 16, 64));
      m = fmaxf(m, __shfl_xor(m, 32, 64));
      mx[qi] = m;
    }

    // ---- defer-max: rescale only when a row max grew past threshold ----
    bool ok = (mx[0] <= mrun[0] + 8.0f) && (mx[1] <= mrun[1] + 8.0f);
    if (!__all(ok)) {
#pragma unroll
      for (int qi = 0; qi < 2; ++qi) {
        float mn = fmaxf(mrun[qi], mx[qi]);
        float alpha = exp2_fast(mrun[qi] - mn);
        mrun[qi] = mn;
        float al[4];
#pragma unroll
        for (int rg = 0; rg < 4; ++rg) al[rg] = __shfl(alpha, lh * 4 + rg, 64);
#pragma unroll
        for (int dt = 0; dt < 4; ++dt)
#pragma unroll
          for (int rg = 0; rg < 4; ++rg) o[qi][dt][rg] *= al[rg];
#pragma unroll
        for (int rg = 0; rg < 4; ++rg) o5[qi][rg] *= al[rg];
      }
    }

    // ---- P = 2^(S - m), packed straight into PV A-frags (lane-local) ----
    bf16x8 pa[2][2];
#pragma unroll
    for (int qi = 0; qi < 2; ++qi)
#pragma unroll
      for (int kb = 0; kb < 2; ++kb)
#pragma unroll
        for (int j = 0; j < 8; ++j)
          pa[qi][kb][j] =
              (__bf16)exp2_fast(sacc[qi][2 * kb + (j >> 2)][j & 3] - mrun[qi]);

    // ---- O += P V ; o5 += P ones ----
#pragma unroll
    for (int kb = 0; kb < 2; ++kb) {
#pragma unroll
      for (int dt = 0; dt < 4; ++dt) {
        int row = dt * 16 + lr;
        bf16x8 vb = *(const bf16x8*)((char*)vt_lds + row * 128 +
                                     ((64 * kb + 16 * lh) ^ ((row & 7) << 4)));
        o[0][dt] = __builtin_amdgcn_mfma_f32_16x16x32_bf16(pa[0][kb], vb, o[0][dt], 0, 0, 0);
        o[1][dt] = __builtin_amdgcn_mfma_f32_16x16x32_bf16(pa[1][kb], vb, o[1][dt], 0, 0, 0);
      }
      o5[0] = __builtin_amdgcn_mfma_f32_16x16x32_bf16(pa[0][kb], ones, o5[0], 0, 0, 0);
      o5[1] = __builtin_amdgcn_mfma_f32_16x16x32_bf16(pa[1][kb], ones, o5[1], 0, 0, 0);
    }
  }

  // ---- epilogue ----
#pragma unroll
  for (int qi = 0; qi < 2; ++qi) {
    float inv[4];
#pragma unroll
    for (int rg = 0; rg < 4; ++rg) {
      float ls = __shfl(o5[qi][rg], lh * 16, 64);  // D[row=q][col=0]
      inv[rg] = 1.0f / ls;
    }
#pragma unroll
    for (int dt = 0; dt < 4; ++dt)
#pragma unroll
      for (int rg = 0; rg < 4; ++rg) {
        int qrow = qw + qi * 16 + lh * 4 + rg;
        out[(size_t)(b * S_ + qrow) * H_ + h * HD_ + dt * 16 + lr] =
            o[qi][dt][rg] * inv[rg];
      }
  }
}

extern "C" void kernel_launch(void* const* d_in, const int* in_sizes, int n_in,
                              void* d_out, int out_size, void* d_ws, size_t ws_size,
                              hipStream_t stream) {
  const float* emb = (const float*)d_in[0];
  const float* wqkv = (const float*)d_in[1];
  float* out = (float*)d_out;

  // ws layout (70 MB): abf 16MB | wtb 6MB | qkv 48MB. vt aliases abf.
  unsigned short* abf = (unsigned short*)d_ws;
  unsigned short* wtb = abf + (size_t)M_ * H_;
  unsigned short* qkv = wtb + (size_t)N3_ * H_;
  unsigned short* vt = abf;

  cvt_emb_kernel<<<dim3(2048), dim3(256), 0, stream>>>(emb, abf, (M_ * H_) / 4);
  cvt_w_kernel<<<dim3(48, 16), dim3(256), 0, stream>>>(wqkv, wtb);
  qkv_gemm_kernel<<<dim3(1536), dim3(256), 0, stream>>>(abf, wtb, qkv);
  vtrans_kernel<<<dim3(32, 16, 4), dim3(256), 0, stream>>>(qkv, vt);
  attn_kernel<<<dim3(16, 16, 4), dim3(256), 0, stream>>>(qkv, vt, out);
}